// Round 7
// baseline (285.100 us; speedup 1.0000x reference)
//
#include <hip/hip_runtime.h>
#include <hip/hip_bf16.h>

// PeakBinner: out[b, g*50+o] = relu( sum_k x[b, g*250+k] * W[g,o,k] )
// Round 12: single-pass x streaming. All prior kernels had g in the grid ->
// each x element read ~2x (groups overlap 250 cols): 320 MB logical vs 164
// compulsory, pinned at ~3.3 TB/s logical service = ~83us. Now block =
// (16-row panel, ~10-group chunk); it streams its rows once, staging 250-col
// half-slabs (bf16) into a 4-slot LDS ring; group g consumes slabs (g,g+1),
// each slab staged ONCE -> logical x = 172 MB, contiguous forward streams.
// W repacked half-aligned (p: 0-249=k0-249, 250-255=0, 256-505=k250-499,
// 506-511=0) so MFMA k-slices never cross a slab boundary; W zeros kill
// x-junk in pad cols. One lgkm-barrier per g; no vmcnt drains (all loads
// reg-staged; compiler dependency waits are exact). 33.8 KB LDS, 4 blk/CU,
// grid 256x4 = 1024 blocks all resident. ~110 VGPR (cap 128).

constexpr int INPUT  = 10000;
constexpr int GROUPS = 39;
constexpr int HALF   = 250;
constexpr int OPG    = 50;
constexpr int OUTW   = 1950;
constexpr int KP     = 512;          // padded K (half-aligned layout)
constexpr int BMT    = 16;           // rows per panel
constexpr int LDH    = 264;          // shorts/row in half-slab (256 data + 8 pad)
constexpr int SLOT   = BMT * LDH;    // 4224 shorts = 8448 B per ring slot

__device__ __hip_bfloat16 Wb[GROUPS * OPG * KP];   // 2.0 MB, L2-resident

typedef __attribute__((ext_vector_type(8))) short    short8;
typedef __attribute__((ext_vector_type(4))) float    float4v;
typedef __attribute__((ext_vector_type(2))) unsigned uint2v;

#define LGKM_BAR() do { \
    asm volatile("s_waitcnt lgkmcnt(0)" ::: "memory"); \
    __builtin_amdgcn_sched_barrier(0); \
    __builtin_amdgcn_s_barrier(); \
    __builtin_amdgcn_sched_barrier(0); \
} while (0)

__device__ __forceinline__ unsigned bf2pack(float a, float b) {
    union { float f; unsigned u; } x, y; x.f = a; y.f = b;
    unsigned lo = (x.u + 0x7fffu + ((x.u >> 16) & 1u)) >> 16;
    unsigned hi = (y.u + 0x7fffu + ((y.u >> 16) & 1u)) & 0xffff0000u;
    return hi | lo;
}

// Wb[g][o][p]: p<250 -> W[k=p]; 250..255 -> 0; 256..505 -> W[k=p-6]; >=506 -> 0
__global__ void prep_w(const float* __restrict__ W) {
    const int slot = blockIdx.x * 256 + threadIdx.x;     // dword slots
    if (slot >= GROUPS * OPG * (KP / 2)) return;
    const int go = slot >> 8;                // /(KP/2)
    const int pd = (slot & 255) * 2;         // p, p+1 (regions even-aligned)
    float2 v = {0.f, 0.f};
    if (pd < 250)                      v = *(const float2*)(W + (size_t)go * 500 + pd);
    else if (pd >= 256 && pd < 506)    v = *(const float2*)(W + (size_t)go * 500 + pd - 6);
    ((unsigned*)Wb)[slot] = bf2pack(v.x, v.y);
}

__global__ __launch_bounds__(256, 4)
void peak_binner_kernel(const float* __restrict__ x,
                        float* __restrict__ out, int batch)
{
    __shared__ __align__(16) short As[4 * SLOT];   // 33,792 B -> 4 blocks/CU

    const int my   = blockIdx.x;                   // 16-row panel
    const int gc   = blockIdx.y;                   // g-chunk
    const int g0   = gc * 10;
    const int NG   = (gc < 3) ? 10 : 9;            // groups in chunk (10,10,10,9)
    const int tid  = threadIdx.x;
    const int lane = tid & 63;
    const int wave = tid >> 6;
    const int fm   = lane & 15;
    const int l4   = lane >> 4;
    const int nb   = (wave == 3) ? 34 : wave * 16; // wave n-rows nb..nb+15

    // wave stages rows wave*4..wave*4+3; lane covers float cols 4*lane..+3
    const float* xr0 = x + (size_t)(my * BMT + wave * 4) * INPUT + 4 * lane;
    const __hip_bfloat16* wp = Wb + ((size_t)g0 * OPG + nb + fm) * KP + l4 * 8;

    float4v vS[4];
    short8  bfrag[16];
    float4v acc;

    auto LOADB = [&]() {                           // 16 dwordx4, L2-hit
        #pragma unroll
        for (int j = 0; j < 16; ++j) bfrag[j] = *(const short8*)(wp + j * 32);
    };

    auto ISSUE = [&](int h) {                      // 4 dwordx4 per lane
        const int gh = g0 + h;                     // global half 0..39
        const float* p0 = xr0 + gh * HALF;
        if (gh != 39) {                            // cols gh*250+4*lane..+3 <= 9755 OK
            #pragma unroll
            for (int j = 0; j < 4; ++j)
                vS[j] = *(const float4v*)(p0 + (size_t)j * INPUT);
        } else {                                   // last half: avoid OOB past col 9999
            #pragma unroll
            for (int j = 0; j < 4; ++j) {
                if (lane < 62)        vS[j] = *(const float4v*)(p0 + (size_t)j * INPUT);
                else if (lane == 62) { float2 t = *(const float2*)(p0 + (size_t)j * INPUT);
                                       vS[j] = float4v{t.x, t.y, 0.f, 0.f}; }
                else                   vS[j] = float4v{0.f, 0.f, 0.f, 0.f};
            }
        }
    };

    auto CONVERT = [&](int s) {                    // 8 packs + 4 ds_write_b64
        #pragma unroll
        for (int j = 0; j < 4; ++j) {
            uint2v w;
            w[0] = bf2pack(vS[j][0], vS[j][1]);
            w[1] = bf2pack(vS[j][2], vS[j][3]);
            *(uint2v*)&As[s * SLOT + (wave * 4 + j) * LDH + 4 * lane] = w;
        }
    };

    auto COMPUTE = [&](int sA, int sB) {           // 16 ds_read_b128 + 16 MFMA
        acc = float4v{0.f, 0.f, 0.f, 0.f};
        const int ab = fm * LDH + l4 * 8;
        __builtin_amdgcn_s_setprio(1);
        #pragma unroll
        for (int kk = 0; kk < 8; ++kk) {           // p 0..255 in slab sA
            const short8 a = *(const short8*)&As[sA * SLOT + ab + kk * 32];
            acc = __builtin_amdgcn_mfma_f32_16x16x32_bf16(a, bfrag[kk], acc, 0, 0, 0);
        }
        #pragma unroll
        for (int kk = 0; kk < 8; ++kk) {           // p 256..511 in slab sB
            const short8 a = *(const short8*)&As[sB * SLOT + ab + kk * 32];
            acc = __builtin_amdgcn_mfma_f32_16x16x32_bf16(a, bfrag[8 + kk], acc, 0, 0, 0);
        }
        __builtin_amdgcn_s_setprio(0);
    };

    auto EPI = [&](int g) {                        // 4 dword stores (exec-masked)
        if (wave < 3 || fm >= 14) {
            const int col = g * OPG + nb + fm;
            #pragma unroll
            for (int reg = 0; reg < 4; ++reg)
                out[(size_t)(my * BMT + l4 * 4 + reg) * OUTW + col] = fmaxf(acc[reg], 0.f);
        }
    };

    // ---- prologue: slabs 0,1 staged; bfrag(g0) in flight under slab-0 wait ----
    ISSUE(0); LOADB(); CONVERT(0);
    ISSUE(1); CONVERT(1);
    LGKM_BAR();

    // ---- g loop: one barrier per group, vmem never drained to 0 ----
    for (int i = 0; i < NG; ++i) {
        if (i + 2 <= NG) ISSUE(i + 2);             // stream next half-slab
        COMPUTE(i & 3, (i + 1) & 3);
        EPI(g0 + i);
        wp += (size_t)OPG * KP;
        if (i + 1 < NG) LOADB();                   // next g's B; covered by
        if (i + 2 <= NG) CONVERT((i + 2) & 3);     //   convert+barrier+ds_reads
        LGKM_BAR();
    }
}

extern "C" void kernel_launch(void* const* d_in, const int* in_sizes, int n_in,
                              void* d_out, int out_size, void* d_ws, size_t ws_size,
                              hipStream_t stream) {
    const float* x = (const float*)d_in[0];   // (batch, 10000) fp32
    const float* W = (const float*)d_in[1];   // (39, 50, 500) fp32
    float* out     = (float*)d_out;           // (batch, 1950) fp32

    const int batch = in_sizes[0] / INPUT;    // 4096

    // prep: W fp32 -> Wb bf16 half-aligned layout
    const int slots = GROUPS * OPG * (KP / 2);            // 499,200
    prep_w<<<(slots + 255) / 256, 256, 0, stream>>>(W);

    dim3 grid(batch / BMT, 4);                            // 256 x 4 = 1024
    peak_binner_kernel<<<grid, dim3(256), 0, stream>>>(x, out, batch);
}

// Round 8
// 272.045 us; speedup vs baseline: 1.0480x; 1.0480x over previous
//
#include <hip/hip_runtime.h>
#include <hip/hip_bf16.h>

// PeakBinner: out[b, g*50+o] = relu( sum_k x[b, g*250+k] * W[g,o,k] )
// Round 13: streaming structure (96 MB fetch, round 12) + fixed B pipeline.
// Round-12 failed on B: VGPR=56 showed bfrag never stayed resident; 16 L2
// loads per g serialized inside compute at 32% occupancy. Now: BMT=32 panels
// (512 blocks, 2/CU) halve per-CU B traffic and double compute per g-iter;
// B double-buffered in registers (bfA/bfB, 128 VGPR) loaded a FULL iteration
// ahead; x staged 2 iterations ahead (vS0/vS1 alternate, slab issued at iter
// i converts at iter i+1). 3-slot LDS ring 50.7 KB (2 blk/CU); one
// lgkm-barrier per g; no vmcnt drains (compiler per-register counted waits);
// sched_barrier(0) fences pin phase placement. launch_bounds(256,2) -> VGPR
// cap 256 (est ~220: bfA 64 + bfB 64 + vS 64 + acc 8 + addr).

constexpr int INPUT  = 10000;
constexpr int GROUPS = 39;
constexpr int HALF   = 250;
constexpr int OPG    = 50;
constexpr int OUTW   = 1950;
constexpr int KP     = 512;          // padded K (half-aligned W layout)
constexpr int BMT    = 32;           // rows per panel
constexpr int LDH    = 264;          // shorts/row in half-slab (256 data + 8 pad)
constexpr int SLOT   = BMT * LDH;    // 8448 shorts = 16,896 B per ring slot

__device__ __hip_bfloat16 Wb[GROUPS * OPG * KP];   // 2.0 MB, L2-resident

typedef __attribute__((ext_vector_type(8))) short    short8;
typedef __attribute__((ext_vector_type(4))) float    float4v;
typedef __attribute__((ext_vector_type(2))) unsigned uint2v;

#define FENCE() __builtin_amdgcn_sched_barrier(0)
#define LGKM_BAR() do { \
    asm volatile("s_waitcnt lgkmcnt(0)" ::: "memory"); \
    __builtin_amdgcn_sched_barrier(0); \
    __builtin_amdgcn_s_barrier(); \
    __builtin_amdgcn_sched_barrier(0); \
} while (0)

__device__ __forceinline__ unsigned bf2pack(float a, float b) {
    union { float f; unsigned u; } x, y; x.f = a; y.f = b;
    unsigned lo = (x.u + 0x7fffu + ((x.u >> 16) & 1u)) >> 16;
    unsigned hi = (y.u + 0x7fffu + ((y.u >> 16) & 1u)) & 0xffff0000u;
    return hi | lo;
}

// Wb[g][o][p]: p<250 -> W[k=p]; 250..255 -> 0; 256..505 -> W[k=p-6]; >=506 -> 0
__global__ void prep_w(const float* __restrict__ W) {
    const int slot = blockIdx.x * 256 + threadIdx.x;     // dword slots
    if (slot >= GROUPS * OPG * (KP / 2)) return;
    const int go = slot >> 8;                // /(KP/2)
    const int pd = (slot & 255) * 2;         // p, p+1 (regions even-aligned)
    float2 v = {0.f, 0.f};
    if (pd < 250)                      v = *(const float2*)(W + (size_t)go * 500 + pd);
    else if (pd >= 256 && pd < 506)    v = *(const float2*)(W + (size_t)go * 500 + pd - 6);
    ((unsigned*)Wb)[slot] = bf2pack(v.x, v.y);
}

__global__ __launch_bounds__(256, 2)
void peak_binner_kernel(const float* __restrict__ x,
                        float* __restrict__ out, int batch)
{
    __shared__ __align__(16) short As[3 * SLOT];   // 50,688 B -> 2 blocks/CU

    const int my   = blockIdx.x;                   // 32-row panel
    const int gc   = blockIdx.y;                   // g-chunk
    const int g0   = gc * 10;
    const int NG   = (gc < 3) ? 10 : 9;            // groups in chunk
    const int tid  = threadIdx.x;
    const int lane = tid & 63;
    const int wave = tid >> 6;
    const int fm   = lane & 15;
    const int l4   = lane >> 4;
    const int nb   = (wave == 3) ? 34 : wave * 16; // wave n-rows nb..nb+15

    // staging: wave stages rows wave*8..wave*8+7; lane covers cols 4*lane..+3
    const float* xr0 = x + (size_t)(my * BMT + wave * 8) * INPUT + 4 * lane;
    const __hip_bfloat16* wp = Wb + ((size_t)g0 * OPG + nb + fm) * KP + l4 * 8;

    float4v vS0[8], vS1[8];      // x slab stages, 2 iterations deep
    short8  bfA[16], bfB[16];    // B double buffer
    float4v acc0, acc1;

    auto ISSUE = [&](int h, float4v* v) {          // 8 dwordx4 per lane (HBM)
        const int gh = g0 + h;
        const float* p0 = xr0 + gh * HALF;
        if (gh != 39) {                            // over-read to col+255 is in-bounds
            #pragma unroll
            for (int j = 0; j < 8; ++j)
                v[j] = *(const float4v*)(p0 + (size_t)j * INPUT);
        } else {                                   // last half: guard OOB past col 9999
            #pragma unroll
            for (int j = 0; j < 8; ++j) {
                if (lane < 62)        v[j] = *(const float4v*)(p0 + (size_t)j * INPUT);
                else if (lane == 62) { float2 t = *(const float2*)(p0 + (size_t)j * INPUT);
                                       v[j] = float4v{t.x, t.y, 0.f, 0.f}; }
                else                   v[j] = float4v{0.f, 0.f, 0.f, 0.f};
            }
        }
    };

    auto LOADB = [&](short8* bf) {                 // 16 dwordx4 per lane (L2)
        #pragma unroll
        for (int j = 0; j < 16; ++j) bf[j] = *(const short8*)(wp + j * 32);
    };

    auto CONVERT = [&](int s, const float4v* v) {  // 16 packs + 8 ds_write_b64
        #pragma unroll
        for (int j = 0; j < 8; ++j) {
            uint2v w;
            w[0] = bf2pack(v[j][0], v[j][1]);
            w[1] = bf2pack(v[j][2], v[j][3]);
            *(uint2v*)&As[s * SLOT + (wave * 8 + j) * LDH + 4 * lane] = w;
        }
    };

    auto COMPUTE = [&](int sA, int sB, const short8* bf) {  // 32 ds_read + 32 MFMA
        acc0 = float4v{0.f, 0.f, 0.f, 0.f};
        acc1 = float4v{0.f, 0.f, 0.f, 0.f};
        const int ab = fm * LDH + l4 * 8;
        __builtin_amdgcn_s_setprio(1);
        #pragma unroll
        for (int kk = 0; kk < 8; ++kk) {           // p 0..255 in slab sA
            const short8 a0 = *(const short8*)&As[sA * SLOT + ab + kk * 32];
            const short8 a1 = *(const short8*)&As[sA * SLOT + ab + 16 * LDH + kk * 32];
            acc0 = __builtin_amdgcn_mfma_f32_16x16x32_bf16(a0, bf[kk], acc0, 0, 0, 0);
            acc1 = __builtin_amdgcn_mfma_f32_16x16x32_bf16(a1, bf[kk], acc1, 0, 0, 0);
        }
        #pragma unroll
        for (int kk = 0; kk < 8; ++kk) {           // p 256..511 in slab sB
            const short8 a0 = *(const short8*)&As[sB * SLOT + ab + kk * 32];
            const short8 a1 = *(const short8*)&As[sB * SLOT + ab + 16 * LDH + kk * 32];
            acc0 = __builtin_amdgcn_mfma_f32_16x16x32_bf16(a0, bf[8 + kk], acc0, 0, 0, 0);
            acc1 = __builtin_amdgcn_mfma_f32_16x16x32_bf16(a1, bf[8 + kk], acc1, 0, 0, 0);
        }
        __builtin_amdgcn_s_setprio(0);
    };

    auto EPI = [&](int g) {                        // 8 dword stores (exec-masked)
        if (wave < 3 || fm >= 14) {
            const int col = g * OPG + nb + fm;
            const size_t r0 = (size_t)(my * BMT + l4 * 4) * OUTW + col;
            #pragma unroll
            for (int reg = 0; reg < 4; ++reg) {
                out[r0 + (size_t)reg * OUTW]        = fmaxf(acc0[reg], 0.f);
                out[r0 + (size_t)(16 + reg) * OUTW] = fmaxf(acc1[reg], 0.f);
            }
        }
    };

    // ---- prologue: slabs 0,1 staged; slab 2 + B(g0) in flight ----
    ISSUE(0, vS0); ISSUE(1, vS1); LOADB(bfA);
    FENCE();
    CONVERT(0, vS0); CONVERT(1, vS1);
    ISSUE(2, vS0);
    LGKM_BAR();

    // ---- g loop: even/odd unrolled for static buffer naming (rule #20) ----
    for (int i = 0;; i += 2) {
        {   // even i: compute bfA, prefetch B(g_{i+1})->bfB, x slab(i+3)->vS1
            if (i + 3 <= NG) ISSUE(i + 3, vS1);
            if (i + 1 < NG) { wp += (size_t)OPG * KP; LOADB(bfB); }
            FENCE();
            COMPUTE(i % 3, (i + 1) % 3, bfA);
            EPI(g0 + i);
            FENCE();
            if (i + 2 <= NG) CONVERT((i + 2) % 3, vS0);   // staged 1 iter ago
            LGKM_BAR();
        }
        if (i + 1 >= NG) break;
        {   // odd k: compute bfB, prefetch B(g_{k+1})->bfA, x slab(k+3)->vS0
            const int k = i + 1;
            if (k + 3 <= NG) ISSUE(k + 3, vS0);
            if (k + 1 < NG) { wp += (size_t)OPG * KP; LOADB(bfA); }
            FENCE();
            COMPUTE(k % 3, (k + 1) % 3, bfB);
            EPI(g0 + k);
            FENCE();
            if (k + 2 <= NG) CONVERT((k + 2) % 3, vS1);
            LGKM_BAR();
        }
        if (i + 2 >= NG) break;
    }
}

extern "C" void kernel_launch(void* const* d_in, const int* in_sizes, int n_in,
                              void* d_out, int out_size, void* d_ws, size_t ws_size,
                              hipStream_t stream) {
    const float* x = (const float*)d_in[0];   // (batch, 10000) fp32
    const float* W = (const float*)d_in[1];   // (39, 50, 500) fp32
    float* out     = (float*)d_out;           // (batch, 1950) fp32

    const int batch = in_sizes[0] / INPUT;    // 4096

    // prep: W fp32 -> Wb bf16 half-aligned layout
    const int slots = GROUPS * OPG * (KP / 2);            // 499,200
    prep_w<<<(slots + 255) / 256, 256, 0, stream>>>(W);

    dim3 grid((batch + BMT - 1) / BMT, 4);                // 128 x 4 = 512
    peak_binner_kernel<<<grid, dim3(256), 0, stream>>>(x, out, batch);
}